// Round 5
// baseline (127.178 us; speedup 1.0000x reference)
//
#include <hip/hip_runtime.h>
#include <hip/hip_bf16.h>

typedef __attribute__((ext_vector_type(4))) float f32x4;
typedef __attribute__((ext_vector_type(8))) short s16x8;

static constexpr int Bn = 32;
static constexpr int Tn = 4096;
static constexpr int Dn = 256;
static constexpr int Un = 256;
static constexpr int CTX_C = 16;

// fp32 -> bf16 round-to-nearest-even
__device__ __forceinline__ ushort f2bf(float f) {
    unsigned x = __float_as_uint(f);
    x += 0x7fffu + ((x >> 16) & 1u);
    return (ushort)(x >> 16);
}

// stable fast tanh: tanh(x) = sign(x) * (1 - e) / (1 + e), e = exp(-2|x|)
__device__ __forceinline__ float fast_tanh(float x) {
    float ax = fabsf(x);
    float e = __expf(-2.0f * ax);
    float r = __fdividef(1.0f - e, 1.0f + e);
    return copysignf(r, x);
}

// K0: W1T[u][d] = bf16(W1[d][u])
__global__ __launch_bounds__(256) void k_w1t(const float* __restrict__ W1,
                                             ushort* __restrict__ W1T) {
    const int u = blockIdx.x, d = threadIdx.x;
    W1T[u * Dn + d] = f2bf(W1[d * Un + u]);
}

// K1: qb[b][u] = sum_d query[b][d]*W2[d][u] + b1[u] + b2[u]
__global__ __launch_bounds__(256) void k_qproj(const float* __restrict__ query,
                                               const float* __restrict__ W2,
                                               const float* __restrict__ b1,
                                               const float* __restrict__ b2,
                                               float* __restrict__ qb) {
    __shared__ float qs[Dn];
    const int b = blockIdx.x, u = threadIdx.x;
    qs[u] = query[b * Dn + u];
    __syncthreads();
    float acc = b1[u] + b2[u];
    #pragma unroll 8
    for (int d = 0; d < Dn; ++d) acc += qs[d] * W2[d * Un + u];
    qb[b * Un + u] = acc;
}

// K2: MFMA score GEMM, latency-structure-first. Block: TWO 64t x 256u tiles,
// 4 waves; wave owns 64t x 64u per tile (acc[4][4]). Tile1's A-loads issue
// into registers BEFORE tile0's k-loop (T14 issue-early/write-late, 8+8
// split) and are converted+written to Al[1] after tile0's epilogue. B streams
// global->reg with 2-deep prefetch. Zero barriers inside k-loops.
__global__ __launch_bounds__(256, 2) void k_score(const float* __restrict__ values,
                                                  const ushort* __restrict__ W1T,
                                                  const float* __restrict__ qb,
                                                  const float* __restrict__ Vw,
                                                  const float* __restrict__ bV,
                                                  float* __restrict__ scores) {
    __shared__ __align__(16) ushort Al[2][64][264];   // 67.6 KB (528B rows)
    __shared__ float sred[4][64];
    const int tid = threadIdx.x;
    const int b = blockIdx.y;
    const int t00 = blockIdx.x * 128;
    const int wid = tid >> 6;
    const int lane = tid & 63;
    const int l15 = lane & 15;
    const int hi = lane >> 4;

    const ushort* wbase = W1T + (size_t)(wid * 64 + l15) * Dn + hi * 8;
    const float* vb0 = values + ((size_t)b * Tn + t00) * Dn;
    const float* vb1 = vb0 + 64 * Dn;

    // epilogue constants (shared by both tiles)
    float Vreg[4], qreg[4];
    #pragma unroll
    for (int ut = 0; ut < 4; ++ut) {
        int u = wid * 64 + ut * 16 + l15;
        Vreg[ut] = Vw[u];
        qreg[ut] = qb[b * Un + u];
    }
    const float bv = bV[0];

    // ---- stage tile 0 directly ----
    #pragma unroll
    for (int i = 0; i < 8; ++i) {
        int flat = i * 2048 + tid * 8;
        int row = flat >> 8, col = flat & 255;
        const float4 f0 = *(const float4*)&vb0[row * Dn + col];
        const float4 f1 = *(const float4*)&vb0[row * Dn + col + 4];
        s16x8 p;
        p[0] = (short)f2bf(f0.x); p[1] = (short)f2bf(f0.y);
        p[2] = (short)f2bf(f0.z); p[3] = (short)f2bf(f0.w);
        p[4] = (short)f2bf(f1.x); p[5] = (short)f2bf(f1.y);
        p[6] = (short)f2bf(f1.z); p[7] = (short)f2bf(f1.w);
        *(s16x8*)&Al[0][row][col] = p;
    }
    __syncthreads();

    f32x4 pA[8], pB[8];  // tile-1 staging registers (issue-early)

    #pragma unroll 1
    for (int tile = 0; tile < 2; ++tile) {
        // B prefetch, 2-deep
        s16x8 bfn0[4], bfn1[4];
        #pragma unroll
        for (int ut = 0; ut < 4; ++ut)
            bfn0[ut] = *(const s16x8*)&wbase[(size_t)ut * 16 * Dn];
        #pragma unroll
        for (int ut = 0; ut < 4; ++ut)
            bfn1[ut] = *(const s16x8*)&wbase[(size_t)ut * 16 * Dn + 32];

        if (tile == 0) {  // issue first half of tile-1 A loads
            #pragma unroll
            for (int i = 0; i < 4; ++i) {
                int flat = i * 2048 + tid * 8;
                int row = flat >> 8, col = flat & 255;
                pA[2 * i]     = *(const f32x4*)&vb1[row * Dn + col];
                pA[2 * i + 1] = *(const f32x4*)&vb1[row * Dn + col + 4];
            }
        }

        f32x4 acc[4][4];
        #pragma unroll
        for (int tt = 0; tt < 4; ++tt)
            #pragma unroll
            for (int ut = 0; ut < 4; ++ut) acc[tt][ut] = (f32x4){0.f, 0.f, 0.f, 0.f};

        #pragma unroll
        for (int kc = 0; kc < 8; ++kc) {
            s16x8 bf[4];
            #pragma unroll
            for (int ut = 0; ut < 4; ++ut) { bf[ut] = bfn0[ut]; bfn0[ut] = bfn1[ut]; }
            if (kc < 6) {
                #pragma unroll
                for (int ut = 0; ut < 4; ++ut)
                    bfn1[ut] = *(const s16x8*)&wbase[(size_t)ut * 16 * Dn + (kc + 2) * 32];
            }
            if (tile == 0 && kc == 4) {  // issue second half of tile-1 A loads
                #pragma unroll
                for (int i = 4; i < 8; ++i) {
                    int flat = i * 2048 + tid * 8;
                    int row = flat >> 8, col = flat & 255;
                    pB[2 * (i - 4)]     = *(const f32x4*)&vb1[row * Dn + col];
                    pB[2 * (i - 4) + 1] = *(const f32x4*)&vb1[row * Dn + col + 4];
                }
            }
            const int k0 = kc * 32;
            #pragma unroll
            for (int tt = 0; tt < 4; ++tt) {
                const s16x8 af = *(const s16x8*)&Al[tile][tt * 16 + l15][k0 + hi * 8];
                #pragma unroll
                for (int ut = 0; ut < 4; ++ut)
                    acc[tt][ut] = __builtin_amdgcn_mfma_f32_16x16x32_bf16(af, bf[ut], acc[tt][ut], 0, 0, 0);
            }
        }

        // epilogue: acc[tt][ut][i] = proj[t=t00+tile*64+tt*16+hi*4+i][u=wid*64+ut*16+l15]
        float ps[4][4];
        #pragma unroll
        for (int tt = 0; tt < 4; ++tt)
            #pragma unroll
            for (int i = 0; i < 4; ++i) ps[tt][i] = 0.f;
        #pragma unroll
        for (int tt = 0; tt < 4; ++tt)
            #pragma unroll
            for (int ut = 0; ut < 4; ++ut)
                #pragma unroll
                for (int i = 0; i < 4; ++i)
                    ps[tt][i] += fast_tanh(acc[tt][ut][i] + qreg[ut]) * Vreg[ut];

        #pragma unroll
        for (int tt = 0; tt < 4; ++tt)
            #pragma unroll
            for (int i = 0; i < 4; ++i) {
                float v = ps[tt][i];
                v += __shfl_xor(v, 1, 64);
                v += __shfl_xor(v, 2, 64);
                v += __shfl_xor(v, 4, 64);
                v += __shfl_xor(v, 8, 64);
                if (l15 == 0) sred[wid][tt * 16 + hi * 4 + i] = v;
            }
        __syncthreads();
        if (tid < 64)
            scores[b * Tn + t00 + tile * 64 + tid] =
                sred[0][tid] + sred[1][tid] + sred[2][tid] + sred[3][tid] + bv;

        if (tile == 0) {  // write-late: convert tile-1 regs -> Al[1]
            #pragma unroll
            for (int i = 0; i < 8; ++i) {
                int flat = i * 2048 + tid * 8;
                int row = flat >> 8, col = flat & 255;
                const f32x4 f0 = (i < 4) ? pA[2 * i] : pB[2 * (i - 4)];
                const f32x4 f1 = (i < 4) ? pA[2 * i + 1] : pB[2 * (i - 4) + 1];
                s16x8 p;
                p[0] = (short)f2bf(f0[0]); p[1] = (short)f2bf(f0[1]);
                p[2] = (short)f2bf(f0[2]); p[3] = (short)f2bf(f0[3]);
                p[4] = (short)f2bf(f1[0]); p[5] = (short)f2bf(f1[1]);
                p[6] = (short)f2bf(f1[2]); p[7] = (short)f2bf(f1[3]);
                *(s16x8*)&Al[1][row][col] = p;
            }
            __syncthreads();
        }
    }
}

// K3: softmax over T per batch, in place.
__global__ __launch_bounds__(256) void k_softmax(const float* __restrict__ scores,
                                                 float* __restrict__ attn) {
    const int b = blockIdx.x, tid = threadIdx.x;
    __shared__ float redm[4];
    __shared__ float reds[4];
    float s[16];
    float m = -1e30f;
    #pragma unroll
    for (int k = 0; k < 16; ++k) {
        s[k] = scores[b * Tn + k * 256 + tid];
        m = fmaxf(m, s[k]);
    }
    #pragma unroll
    for (int off = 32; off > 0; off >>= 1) m = fmaxf(m, __shfl_xor(m, off, 64));
    const int wid = tid >> 6;
    if ((tid & 63) == 0) redm[wid] = m;
    __syncthreads();
    m = fmaxf(fmaxf(redm[0], redm[1]), fmaxf(redm[2], redm[3]));
    float sum = 0.f;
    #pragma unroll
    for (int k = 0; k < 16; ++k) { s[k] = __expf(s[k] - m); sum += s[k]; }
    #pragma unroll
    for (int off = 32; off > 0; off >>= 1) sum += __shfl_xor(sum, off, 64);
    if ((tid & 63) == 0) reds[wid] = sum;
    __syncthreads();
    sum = reds[0] + reds[1] + reds[2] + reds[3];
    const float inv = 1.0f / sum;
    #pragma unroll
    for (int k = 0; k < 16; ++k) attn[b * Tn + k * 256 + tid] = s[k] * inv;
}

// K4: context partials, deterministic.
__global__ __launch_bounds__(256) void k_ctx_partial(const float* __restrict__ values,
                                                     const float* __restrict__ attn,
                                                     float* __restrict__ partial) {
    const int c = blockIdx.x, b = blockIdx.y, tid = threadIdx.x;
    const int d4 = (tid & 63) * 4, tg = tid >> 6;
    float4 a = make_float4(0.f, 0.f, 0.f, 0.f);
    const float* vbase = values + (size_t)b * Tn * Dn;
    const int tstart = c * (Tn / CTX_C);
    for (int t = tstart + tg; t < tstart + Tn / CTX_C; t += 4) {
        const float w = attn[b * Tn + t];  // wave-uniform
        const float4 v = *(const float4*)&vbase[(size_t)t * Dn + d4];
        a.x += w * v.x; a.y += w * v.y; a.z += w * v.z; a.w += w * v.w;
    }
    __shared__ float4 red[4][64];
    red[tg][tid & 63] = a;
    __syncthreads();
    if (tg == 0) {
        const float4 r0 = red[0][tid], r1 = red[1][tid], r2 = red[2][tid], r3 = red[3][tid];
        a.x = r0.x + r1.x + r2.x + r3.x;
        a.y = r0.y + r1.y + r2.y + r3.y;
        a.z = r0.z + r1.z + r2.z + r3.z;
        a.w = r0.w + r1.w + r2.w + r3.w;
        *(float4*)&partial[((size_t)b * CTX_C + c) * Dn + d4] = a;
    }
}

// K5: reduce the CTX_C partials per batch.
__global__ __launch_bounds__(256) void k_ctx_final(const float* __restrict__ partial,
                                                   float* __restrict__ context) {
    const int b = blockIdx.x, d = threadIdx.x;
    float a = 0.f;
    #pragma unroll
    for (int c = 0; c < CTX_C; ++c) a += partial[((size_t)b * CTX_C + c) * Dn + d];
    context[b * Dn + d] = a;
}

extern "C" void kernel_launch(void* const* d_in, const int* in_sizes, int n_in,
                              void* d_out, int out_size, void* d_ws, size_t ws_size,
                              hipStream_t stream) {
    const float* query  = (const float*)d_in[0];
    const float* values = (const float*)d_in[1];
    const float* W1     = (const float*)d_in[2];
    const float* b1     = (const float*)d_in[3];
    const float* W2     = (const float*)d_in[4];
    const float* b2     = (const float*)d_in[5];
    const float* Vw     = (const float*)d_in[6];
    const float* bV     = (const float*)d_in[7];

    float* context = (float*)d_out;            // [B,D]
    float* attn    = (float*)d_out + Bn * Dn;  // [B,T,1] — score scratch then softmax in place
    float*  partial = (float*)d_ws;                         // [B, CTX_C, D]
    float*  qb      = partial + Bn * CTX_C * Dn;            // [B, U]
    ushort* W1T     = (ushort*)(qb + Bn * Un);              // [U, D] bf16

    k_w1t<<<dim3(Un), dim3(Dn), 0, stream>>>(W1, W1T);
    k_qproj<<<dim3(Bn), dim3(256), 0, stream>>>(query, W2, b1, b2, qb);
    k_score<<<dim3(Tn / 128, Bn), dim3(256), 0, stream>>>(values, W1T, qb, Vw, bV, attn);
    k_softmax<<<dim3(Bn), dim3(256), 0, stream>>>(attn, attn);
    k_ctx_partial<<<dim3(CTX_C, Bn), dim3(256), 0, stream>>>(values, attn, partial);
    k_ctx_final<<<dim3(Bn), dim3(256), 0, stream>>>(partial, context);
}

// Round 6
// 78.459 us; speedup vs baseline: 1.6209x; 1.6209x over previous
//
#include <hip/hip_runtime.h>
#include <hip/hip_bf16.h>

typedef __attribute__((ext_vector_type(4))) float f32x4;
typedef __attribute__((ext_vector_type(8))) short s16x8;
typedef __attribute__((ext_vector_type(4))) short s16x4;

static constexpr int Bn = 32;
static constexpr int Tn = 4096;
static constexpr int Dn = 256;
static constexpr int Un = 256;
static constexpr int CH = Tn / 64;   // 64 t-chunks per batch

// fp32 -> bf16 round-to-nearest-even
__device__ __forceinline__ ushort f2bf(float f) {
    unsigned x = __float_as_uint(f);
    x += 0x7fffu + ((x >> 16) & 1u);
    return (ushort)(x >> 16);
}
__device__ __forceinline__ float bf2f(ushort u) {
    return __uint_as_float(((unsigned)u) << 16);
}

// stable fast tanh: tanh(x) = sign(x) * (1 - e) / (1 + e), e = exp(-2|x|)
__device__ __forceinline__ float fast_tanh(float x) {
    float ax = fabsf(x);
    float e = __expf(-2.0f * ax);
    float r = __fdividef(1.0f - e, 1.0f + e);
    return copysignf(r, x);
}

// K0: fused prep. Blocks 0..255: W1T[u][d] = bf16(W1[d][u]).
// Blocks 256..287: qb[b][u] = query[b]·W2[:,u] + b1[u] + b2[u].
__global__ __launch_bounds__(256) void k_prep(const float* __restrict__ W1,
                                              ushort* __restrict__ W1T,
                                              const float* __restrict__ query,
                                              const float* __restrict__ W2,
                                              const float* __restrict__ b1,
                                              const float* __restrict__ b2,
                                              float* __restrict__ qb) {
    __shared__ float qs[Dn];
    if (blockIdx.x < 256) {
        const int u = blockIdx.x, d = threadIdx.x;
        W1T[u * Dn + d] = f2bf(W1[d * Un + u]);
    } else {
        const int b = blockIdx.x - 256, u = threadIdx.x;
        qs[u] = query[b * Dn + u];
        __syncthreads();
        float acc = b1[u] + b2[u];
        #pragma unroll 8
        for (int d = 0; d < Dn; ++d) acc += qs[d] * W2[d * Un + u];
        qb[b * Un + u] = acc;
    }
}

// K1: fused score GEMM + flash partials. Block: 64t x 256u, 4 waves; wave owns
// 64t x 64u (acc[4][4]). A staged once to LDS (528B rows, 2-way free); B
// streams global->reg (L2-hot W1T) with DEPTH-2 prefetch. Zero k-loop
// barriers. Epilogue: tanh·V -> score -> chunk softmax partials (m,S) ->
// weighted bf16-context partial from the LDS A tile (values read ONCE).
__global__ __launch_bounds__(256, 4) void k_fused(const float* __restrict__ values,
                                                  const ushort* __restrict__ W1T,
                                                  const float* __restrict__ qb,
                                                  const float* __restrict__ Vw,
                                                  const float* __restrict__ bV,
                                                  float* __restrict__ scores,
                                                  float* __restrict__ pm,
                                                  float* __restrict__ ps,
                                                  float* __restrict__ pctx) {
    __shared__ __align__(16) ushort Al[64][264];   // 33.8 KB
    __shared__ float sred[4][64];                  // 1 KB
    __shared__ float slp[64];                      // 256 B
    __shared__ f32x4 red[4][64];                   // 4 KB
    const int tid = threadIdx.x;
    const int b = blockIdx.y;
    const int c = blockIdx.x;          // t-chunk
    const int t0 = c * 64;
    const int wid = tid >> 6;
    const int lane = tid & 63;
    const int l15 = lane & 15;
    const int hi = lane >> 4;

    // Stage A: 64 rows x 256 d, fp32 coalesced -> bf16 -> LDS
    const float* vbase = values + ((size_t)b * Tn + t0) * Dn;
    #pragma unroll
    for (int i = 0; i < 8; ++i) {
        int flat = i * 2048 + tid * 8;
        int row = flat >> 8, col = flat & 255;
        const float4 f0 = *(const float4*)&vbase[row * Dn + col];
        const float4 f1 = *(const float4*)&vbase[row * Dn + col + 4];
        s16x8 p;
        p[0] = (short)f2bf(f0.x); p[1] = (short)f2bf(f0.y);
        p[2] = (short)f2bf(f0.z); p[3] = (short)f2bf(f0.w);
        p[4] = (short)f2bf(f1.x); p[5] = (short)f2bf(f1.y);
        p[6] = (short)f2bf(f1.z); p[7] = (short)f2bf(f1.w);
        *(s16x8*)&Al[row][col] = p;
    }

    const ushort* wbase = W1T + (size_t)(wid * 64 + l15) * Dn + hi * 8;

    f32x4 acc[4][4];
    #pragma unroll
    for (int tt = 0; tt < 4; ++tt)
        #pragma unroll
        for (int ut = 0; ut < 4; ++ut) acc[tt][ut] = (f32x4){0.f, 0.f, 0.f, 0.f};

    // B prefetch depth 2
    s16x8 bfn0[4], bfn1[4];
    #pragma unroll
    for (int ut = 0; ut < 4; ++ut)
        bfn0[ut] = *(const s16x8*)&wbase[(size_t)ut * 16 * Dn];
    #pragma unroll
    for (int ut = 0; ut < 4; ++ut)
        bfn1[ut] = *(const s16x8*)&wbase[(size_t)ut * 16 * Dn + 32];

    __syncthreads();  // A tile visible

    #pragma unroll
    for (int kc = 0; kc < 8; ++kc) {
        s16x8 bf[4];
        #pragma unroll
        for (int ut = 0; ut < 4; ++ut) { bf[ut] = bfn0[ut]; bfn0[ut] = bfn1[ut]; }
        if (kc < 6) {
            #pragma unroll
            for (int ut = 0; ut < 4; ++ut)
                bfn1[ut] = *(const s16x8*)&wbase[(size_t)ut * 16 * Dn + (kc + 2) * 32];
        }
        const int k0 = kc * 32;
        s16x8 af[4];
        #pragma unroll
        for (int tt = 0; tt < 4; ++tt)
            af[tt] = *(const s16x8*)&Al[tt * 16 + l15][k0 + hi * 8];
        #pragma unroll
        for (int tt = 0; tt < 4; ++tt)
            #pragma unroll
            for (int ut = 0; ut < 4; ++ut)
                acc[tt][ut] = __builtin_amdgcn_mfma_f32_16x16x32_bf16(af[tt], bf[ut], acc[tt][ut], 0, 0, 0);
    }

    // epilogue constants after k-loop (keeps loop VGPR low)
    float Vreg[4], qreg[4];
    #pragma unroll
    for (int ut = 0; ut < 4; ++ut) {
        int u = wid * 64 + ut * 16 + l15;
        Vreg[ut] = Vw[u];
        qreg[ut] = qb[b * Un + u];
    }

    // acc[tt][ut][i] = proj[t=t0+tt*16+hi*4+i][u=wid*64+ut*16+l15]
    float psc[4][4];
    #pragma unroll
    for (int tt = 0; tt < 4; ++tt)
        #pragma unroll
        for (int i = 0; i < 4; ++i) psc[tt][i] = 0.f;
    #pragma unroll
    for (int tt = 0; tt < 4; ++tt)
        #pragma unroll
        for (int ut = 0; ut < 4; ++ut)
            #pragma unroll
            for (int i = 0; i < 4; ++i)
                psc[tt][i] += fast_tanh(acc[tt][ut][i] + qreg[ut]) * Vreg[ut];

    #pragma unroll
    for (int tt = 0; tt < 4; ++tt)
        #pragma unroll
        for (int i = 0; i < 4; ++i) {
            float v = psc[tt][i];
            v += __shfl_xor(v, 1, 64);
            v += __shfl_xor(v, 2, 64);
            v += __shfl_xor(v, 4, 64);
            v += __shfl_xor(v, 8, 64);
            if (l15 == 0) sred[wid][tt * 16 + hi * 4 + i] = v;
        }
    __syncthreads();

    // wave 0: final scores + chunk flash partials (m_c, S_c), p -> slp
    if (tid < 64) {
        float s = sred[0][tid] + sred[1][tid] + sred[2][tid] + sred[3][tid] + bV[0];
        scores[b * Tn + t0 + tid] = s;
        float m = s;
        #pragma unroll
        for (int off = 32; off > 0; off >>= 1) m = fmaxf(m, __shfl_xor(m, off, 64));
        float p = __expf(s - m);
        float S = p;
        #pragma unroll
        for (int off = 32; off > 0; off >>= 1) S += __shfl_xor(S, off, 64);
        slp[tid] = p;
        if (tid == 0) { pm[b * CH + c] = m; ps[b * CH + c] = S; }
    }
    __syncthreads();

    // weighted context partial from the bf16 A tile (no second values read)
    const int d4 = (tid & 63) * 4, tg = tid >> 6;
    f32x4 a = (f32x4){0.f, 0.f, 0.f, 0.f};
    #pragma unroll 4
    for (int t = tg; t < 64; t += 4) {
        const float p = slp[t];  // broadcast
        const s16x4 v = *(const s16x4*)&Al[t][d4];
        a[0] += p * bf2f((ushort)v[0]);
        a[1] += p * bf2f((ushort)v[1]);
        a[2] += p * bf2f((ushort)v[2]);
        a[3] += p * bf2f((ushort)v[3]);
    }
    red[tg][tid & 63] = a;
    __syncthreads();
    if (tg == 0) {
        const f32x4 r0 = red[0][tid], r1 = red[1][tid], r2 = red[2][tid], r3 = red[3][tid];
        f32x4 o = r0 + r1 + r2 + r3;
        *(f32x4*)&pctx[((size_t)b * CH + c) * Dn + d4] = o;
    }
}

// K2: per-batch flash reduce: M, S, context; stash {M, S} for the attn pass.
__global__ __launch_bounds__(256) void k_reduce(const float* __restrict__ pm,
                                                const float* __restrict__ ps,
                                                const float* __restrict__ pctx,
                                                float* __restrict__ context,
                                                float* __restrict__ MS) {
    const int b = blockIdx.x, d = threadIdx.x;
    float M = -1e30f;
    #pragma unroll 8
    for (int c = 0; c < CH; ++c) M = fmaxf(M, pm[b * CH + c]);  // broadcast reads
    float S = 0.f, ctx = 0.f;
    #pragma unroll 4
    for (int c = 0; c < CH; ++c) {
        const float w = __expf(pm[b * CH + c] - M);
        S += w * ps[b * CH + c];
        ctx += w * pctx[((size_t)b * CH + c) * Dn + d];
    }
    context[b * Dn + d] = __fdividef(ctx, S);
    if (d == 0) { MS[b * 2] = M; MS[b * 2 + 1] = S; }
}

// K3: attn[b,t] = exp(score - M_b) / S_b, in place over the score buffer.
__global__ __launch_bounds__(256) void k_attn(float* __restrict__ attn,
                                              const float* __restrict__ MS) {
    const int b = blockIdx.y;
    const int base = b * Tn + blockIdx.x * 1024 + threadIdx.x * 4;
    const float M = MS[b * 2];
    const float invS = __fdividef(1.0f, MS[b * 2 + 1]);
    float4 s = *(const float4*)&attn[base];
    s.x = __expf(s.x - M) * invS;
    s.y = __expf(s.y - M) * invS;
    s.z = __expf(s.z - M) * invS;
    s.w = __expf(s.w - M) * invS;
    *(float4*)&attn[base] = s;
}

extern "C" void kernel_launch(void* const* d_in, const int* in_sizes, int n_in,
                              void* d_out, int out_size, void* d_ws, size_t ws_size,
                              hipStream_t stream) {
    const float* query  = (const float*)d_in[0];
    const float* values = (const float*)d_in[1];
    const float* W1     = (const float*)d_in[2];
    const float* b1     = (const float*)d_in[3];
    const float* W2     = (const float*)d_in[4];
    const float* b2     = (const float*)d_in[5];
    const float* Vw     = (const float*)d_in[6];
    const float* bV     = (const float*)d_in[7];

    float* context = (float*)d_out;            // [B,D]
    float* attn    = (float*)d_out + Bn * Dn;  // [B,T,1] — scores, then attn in place

    float*  pctx = (float*)d_ws;                       // [B, CH, D]   = 2 MB
    float*  pm   = pctx + (size_t)Bn * CH * Dn;        // [B, CH]      = 8 KB
    float*  ps   = pm + Bn * CH;                       // [B, CH]      = 8 KB
    float*  qb   = ps + Bn * CH;                       // [B, U]       = 32 KB
    float*  MS   = qb + Bn * Un;                       // [B, 2]
    ushort* W1T  = (ushort*)(MS + Bn * 2);             // [U, D] bf16  = 128 KB

    k_prep<<<dim3(256 + Bn), dim3(256), 0, stream>>>(W1, W1T, query, W2, b1, b2, qb);
    k_fused<<<dim3(CH, Bn), dim3(256), 0, stream>>>(values, W1T, qb, Vw, bV,
                                                    attn, pm, ps, pctx);
    k_reduce<<<dim3(Bn), dim3(256), 0, stream>>>(pm, ps, pctx, context, MS);
    k_attn<<<dim3(Tn / 1024, Bn), dim3(256), 0, stream>>>(attn, MS);
}

// Round 7
// 77.110 us; speedup vs baseline: 1.6493x; 1.0175x over previous
//
#include <hip/hip_runtime.h>
#include <hip/hip_bf16.h>

typedef __attribute__((ext_vector_type(4))) float f32x4;
typedef __attribute__((ext_vector_type(8))) short s16x8;
typedef __attribute__((ext_vector_type(4))) short s16x4;

static constexpr int Bn = 32;
static constexpr int Tn = 4096;
static constexpr int Dn = 256;
static constexpr int Un = 256;
static constexpr int NBLK = 16;   // blocks per batch (256 t-rows each)

// fp32 -> bf16 round-to-nearest-even
__device__ __forceinline__ ushort f2bf(float f) {
    unsigned x = __float_as_uint(f);
    x += 0x7fffu + ((x >> 16) & 1u);
    return (ushort)(x >> 16);
}
__device__ __forceinline__ float bf2f(ushort u) {
    return __uint_as_float(((unsigned)u) << 16);
}

// stable fast tanh: tanh(x) = sign(x) * (1 - e) / (1 + e), e = exp(-2|x|)
__device__ __forceinline__ float fast_tanh(float x) {
    float ax = fabsf(x);
    float e = __expf(-2.0f * ax);
    float r = __fdividef(1.0f - e, 1.0f + e);
    return copysignf(r, x);
}

// K0: fused prep. Blocks 0..255: W1T[u][d] = bf16(W1[d][u]).
// Blocks 256..287: qb[b][u] = query[b]·W2[:,u] + b1[u] + b2[u].
__global__ __launch_bounds__(256) void k_prep(const float* __restrict__ W1,
                                              ushort* __restrict__ W1T,
                                              const float* __restrict__ query,
                                              const float* __restrict__ W2,
                                              const float* __restrict__ b1,
                                              const float* __restrict__ b2,
                                              float* __restrict__ qb) {
    __shared__ float qs[Dn];
    if (blockIdx.x < 256) {
        const int u = blockIdx.x, d = threadIdx.x;
        W1T[u * Dn + d] = f2bf(W1[d * Un + u]);
    } else {
        const int b = blockIdx.x - 256, u = threadIdx.x;
        qs[u] = query[b * Dn + u];
        __syncthreads();
        float acc = b1[u] + b2[u];
        #pragma unroll 8
        for (int d = 0; d < Dn; ++d) acc += qs[d] * W2[d * Un + u];
        qb[b * Un + u] = acc;
    }
}

// K1: persistent-ish fused kernel. Grid 512 blocks = 2/CU, ALL resident (one
// generation). Block owns 256 t-rows = 8 chunks of 32. Pipeline per chunk:
// convert regs->Bl[cur]; barrier; issue chunk i+1 fp32 loads -> regs (a full
// chunk of compute ahead of use); k-loop (zero barriers, B global->reg ring);
// epilogue: tanh·V scores + online flash (running M,S in LDS; per-thread ctx
// in registers, rescaled per chunk). Partials written once per block.
__global__ __launch_bounds__(256, 2) void k_fused(const float* __restrict__ values,
                                                  const ushort* __restrict__ W1T,
                                                  const float* __restrict__ qb,
                                                  const float* __restrict__ Vw,
                                                  const float* __restrict__ bV,
                                                  float* __restrict__ scores,
                                                  float* __restrict__ pM,
                                                  float* __restrict__ pS,
                                                  float* __restrict__ pctx) {
    __shared__ __align__(16) ushort Bl[2][32][264];  // 33 KB dbuf, 528B rows (2-way free)
    __shared__ float sred[4][32];
    __shared__ float slp[32];
    __shared__ float sfac[2];
    __shared__ float runMS[2];
    __shared__ f32x4 cred[4][64];

    const int tid = threadIdx.x;
    const int b = blockIdx.y, blk = blockIdx.x;
    const int wid = tid >> 6, lane = tid & 63;
    const int l15 = lane & 15, hi = lane >> 4;
    const int d4 = (tid & 63) * 4, tg = tid >> 6;

    const float* vbase = values + ((size_t)b * Tn + blk * 256) * Dn;
    const ushort* wbase = W1T + (size_t)(wid * 64 + l15) * Dn + hi * 8;

    float Vreg[4], qreg[4];
    #pragma unroll
    for (int ut = 0; ut < 4; ++ut) {
        int u = wid * 64 + ut * 16 + l15;
        Vreg[ut] = Vw[u];
        qreg[ut] = qb[b * Un + u];
    }
    const float bv = bV[0];

    if (tid == 0) { runMS[0] = -1e30f; runMS[1] = 0.f; }

    // stage chunk 0 into registers (coalesced: consecutive tid -> consecutive 16B)
    f32x4 stg[8];
    #pragma unroll
    for (int i = 0; i < 8; ++i) {
        int idx = i * 256 + tid;
        stg[i] = *(const f32x4*)&vbase[(idx >> 6) * Dn + (idx & 63) * 4];
    }

    f32x4 cacc = (f32x4){0.f, 0.f, 0.f, 0.f};

    #pragma unroll 1
    for (int ck = 0; ck < 8; ++ck) {
        const int cur = ck & 1;

        // convert staged fp32 -> bf16 tile
        #pragma unroll
        for (int i = 0; i < 8; ++i) {
            int idx = i * 256 + tid;
            s16x4 p;
            p[0] = (short)f2bf(stg[i][0]); p[1] = (short)f2bf(stg[i][1]);
            p[2] = (short)f2bf(stg[i][2]); p[3] = (short)f2bf(stg[i][3]);
            *(s16x4*)&Bl[cur][idx >> 6][(idx & 63) * 4] = p;
        }
        __syncthreads();  // B1: tile ready (covers runMS init on ck==0)

        // issue next chunk's loads — they land during this chunk's compute
        if (ck < 7) {
            const float* vb = vbase + (ck + 1) * 32 * Dn;
            #pragma unroll
            for (int i = 0; i < 8; ++i) {
                int idx = i * 256 + tid;
                stg[i] = *(const f32x4*)&vb[(idx >> 6) * Dn + (idx & 63) * 4];
            }
        }

        // B ring (depth-2, L2-hot W1T) + MFMA k-loop, zero barriers
        s16x8 bfn0[4], bfn1[4];
        #pragma unroll
        for (int ut = 0; ut < 4; ++ut)
            bfn0[ut] = *(const s16x8*)&wbase[(size_t)ut * 16 * Dn];
        #pragma unroll
        for (int ut = 0; ut < 4; ++ut)
            bfn1[ut] = *(const s16x8*)&wbase[(size_t)ut * 16 * Dn + 32];

        f32x4 acc[2][4];
        #pragma unroll
        for (int tt = 0; tt < 2; ++tt)
            #pragma unroll
            for (int ut = 0; ut < 4; ++ut) acc[tt][ut] = (f32x4){0.f, 0.f, 0.f, 0.f};

        #pragma unroll
        for (int kc = 0; kc < 8; ++kc) {
            s16x8 bf[4];
            #pragma unroll
            for (int ut = 0; ut < 4; ++ut) { bf[ut] = bfn0[ut]; bfn0[ut] = bfn1[ut]; }
            if (kc < 6) {
                #pragma unroll
                for (int ut = 0; ut < 4; ++ut)
                    bfn1[ut] = *(const s16x8*)&wbase[(size_t)ut * 16 * Dn + (kc + 2) * 32];
            }
            s16x8 af[2];
            #pragma unroll
            for (int tt = 0; tt < 2; ++tt)
                af[tt] = *(const s16x8*)&Bl[cur][tt * 16 + l15][kc * 32 + hi * 8];
            #pragma unroll
            for (int tt = 0; tt < 2; ++tt)
                #pragma unroll
                for (int ut = 0; ut < 4; ++ut)
                    acc[tt][ut] = __builtin_amdgcn_mfma_f32_16x16x32_bf16(af[tt], bf[ut], acc[tt][ut], 0, 0, 0);
        }

        // epilogue: tanh·V, reduce over u
        float psc[2][4];
        #pragma unroll
        for (int tt = 0; tt < 2; ++tt)
            #pragma unroll
            for (int i = 0; i < 4; ++i) psc[tt][i] = 0.f;
        #pragma unroll
        for (int tt = 0; tt < 2; ++tt)
            #pragma unroll
            for (int ut = 0; ut < 4; ++ut)
                #pragma unroll
                for (int i = 0; i < 4; ++i)
                    psc[tt][i] += fast_tanh(acc[tt][ut][i] + qreg[ut]) * Vreg[ut];
        #pragma unroll
        for (int tt = 0; tt < 2; ++tt)
            #pragma unroll
            for (int i = 0; i < 4; ++i) {
                float v = psc[tt][i];
                v += __shfl_xor(v, 1, 64);
                v += __shfl_xor(v, 2, 64);
                v += __shfl_xor(v, 4, 64);
                v += __shfl_xor(v, 8, 64);
                if (l15 == 0) sred[wid][tt * 16 + hi * 4 + i] = v;
            }
        __syncthreads();  // B2

        // wave 0: scores + chunk softmax partials + running (M,S) update
        if (tid < 64) {
            const int row = lane & 31;
            float s = sred[0][row] + sred[1][row] + sred[2][row] + sred[3][row] + bv;
            if (lane < 32) scores[b * Tn + blk * 256 + ck * 32 + row] = s;
            float m = s;
            #pragma unroll
            for (int off = 16; off > 0; off >>= 1) m = fmaxf(m, __shfl_xor(m, off, 64));
            float p = __expf(s - m);
            float S = p;
            #pragma unroll
            for (int off = 16; off > 0; off >>= 1) S += __shfl_xor(S, off, 64);
            if (lane < 32) slp[row] = p;
            if (lane == 0) {
                float Mold = runMS[0];
                float Mnew = fmaxf(Mold, m);
                float sco = __expf(Mold - Mnew);   // 0 on first chunk
                float scc = __expf(m - Mnew);
                sfac[0] = sco; sfac[1] = scc;
                runMS[0] = Mnew;
                runMS[1] = runMS[1] * sco + S * scc;
            }
        }
        __syncthreads();  // B3

        // in-register online context accumulation from the bf16 tile
        const float sco = sfac[0], scc = sfac[1];
        f32x4 loc = (f32x4){0.f, 0.f, 0.f, 0.f};
        #pragma unroll
        for (int t = tg; t < 32; t += 4) {
            const float p = slp[t];
            const s16x4 v = *(const s16x4*)&Bl[cur][t][d4];
            loc[0] += p * bf2f((ushort)v[0]);
            loc[1] += p * bf2f((ushort)v[1]);
            loc[2] += p * bf2f((ushort)v[2]);
            loc[3] += p * bf2f((ushort)v[3]);
        }
        cacc = cacc * sco + loc * scc;
    }

    // block finalize: cross-tg context reduce + partials
    cred[tg][tid & 63] = cacc;
    __syncthreads();
    if (tg == 0) {
        const f32x4 o = cred[0][tid] + cred[1][tid] + cred[2][tid] + cred[3][tid];
        *(f32x4*)&pctx[((size_t)(b * NBLK + blk)) * Dn + d4] = o;
    }
    if (tid == 0) {
        pM[b * NBLK + blk] = runMS[0];
        pS[b * NBLK + blk] = runMS[1];
    }
}

// K2: per-batch flash reduce over NBLK block partials.
__global__ __launch_bounds__(256) void k_reduce(const float* __restrict__ pM,
                                                const float* __restrict__ pS,
                                                const float* __restrict__ pctx,
                                                float* __restrict__ context,
                                                float* __restrict__ MS) {
    const int b = blockIdx.x, d = threadIdx.x;
    float M = -1e30f;
    #pragma unroll
    for (int c = 0; c < NBLK; ++c) M = fmaxf(M, pM[b * NBLK + c]);
    float S = 0.f, ctx = 0.f;
    #pragma unroll
    for (int c = 0; c < NBLK; ++c) {
        const float w = __expf(pM[b * NBLK + c] - M);
        S += w * pS[b * NBLK + c];
        ctx += w * pctx[((size_t)(b * NBLK + c)) * Dn + d];
    }
    context[b * Dn + d] = __fdividef(ctx, S);
    if (d == 0) { MS[b * 2] = M; MS[b * 2 + 1] = S; }
}

// K3: attn[b,t] = exp(score - M_b) / S_b, in place over the score buffer.
__global__ __launch_bounds__(256) void k_attn(float* __restrict__ attn,
                                              const float* __restrict__ MS) {
    const int b = blockIdx.y;
    const int base = b * Tn + blockIdx.x * 1024 + threadIdx.x * 4;
    const float M = MS[b * 2];
    const float invS = __fdividef(1.0f, MS[b * 2 + 1]);
    float4 s = *(const float4*)&attn[base];
    s.x = __expf(s.x - M) * invS;
    s.y = __expf(s.y - M) * invS;
    s.z = __expf(s.z - M) * invS;
    s.w = __expf(s.w - M) * invS;
    *(float4*)&attn[base] = s;
}

extern "C" void kernel_launch(void* const* d_in, const int* in_sizes, int n_in,
                              void* d_out, int out_size, void* d_ws, size_t ws_size,
                              hipStream_t stream) {
    const float* query  = (const float*)d_in[0];
    const float* values = (const float*)d_in[1];
    const float* W1     = (const float*)d_in[2];
    const float* b1     = (const float*)d_in[3];
    const float* W2     = (const float*)d_in[4];
    const float* b2     = (const float*)d_in[5];
    const float* Vw     = (const float*)d_in[6];
    const float* bV     = (const float*)d_in[7];

    float* context = (float*)d_out;            // [B,D]
    float* attn    = (float*)d_out + Bn * Dn;  // [B,T,1] — raw scores, then attn in place

    float*  pctx = (float*)d_ws;                       // [B, NBLK, D] = 512 KB
    float*  pM   = pctx + (size_t)Bn * NBLK * Dn;      // [B, NBLK]
    float*  pS   = pM + Bn * NBLK;                     // [B, NBLK]
    float*  qb   = pS + Bn * NBLK;                     // [B, U]
    float*  MS   = qb + Bn * Un;                       // [B, 2]
    ushort* W1T  = (ushort*)(MS + Bn * 2);             // [U, D] bf16 = 128 KB

    k_prep<<<dim3(256 + Bn), dim3(256), 0, stream>>>(W1, W1T, query, W2, b1, b2, qb);
    k_fused<<<dim3(NBLK, Bn), dim3(256), 0, stream>>>(values, W1T, qb, Vw, bV,
                                                      attn, pM, pS, pctx);
    k_reduce<<<dim3(Bn), dim3(256), 0, stream>>>(pM, pS, pctx, context, MS);
    k_attn<<<dim3(Tn / 1024, Bn), dim3(256), 0, stream>>>(attn, MS);
}